// Round 1
// baseline (813.184 us; speedup 1.0000x reference)
//
#include <hip/hip_runtime.h>
#include <hip/hip_bf16.h>

typedef short bf16x8 __attribute__((ext_vector_type(8)));
typedef float f32x4 __attribute__((ext_vector_type(4)));
typedef unsigned short u16x8 __attribute__((ext_vector_type(8)));

#define DEVI static __device__ __forceinline__

constexpr int Bb = 4, Hh = 16, Ss = 2048, Dd = 64;
constexpr int BH = Bb * Hh;
constexpr float SCALE = 0.125f;                    // 1/sqrt(64)
constexpr long QKV_ELEMS = (long)BH * Ss * Dd;     // 8,388,608

DEVI unsigned short f2bf(float f) {
  __hip_bfloat16 h = __float2bfloat16(f);
  unsigned short u;
  __builtin_memcpy(&u, &h, 2);
  return u;
}
DEVI float bflo(unsigned int u) { unsigned int x = u << 16;        float f; __builtin_memcpy(&f, &x, 4); return f; }
DEVI float bfhi(unsigned int u) { unsigned int x = u & 0xffff0000u; float f; __builtin_memcpy(&f, &x, 4); return f; }

// swizzled byte offset into the P LDS tile: row q (16 rows x 4096B), XOR spreads banks
DEVI int pidx(int q, int k) { return (q << 12) + ((k << 1) ^ ((q & 7) << 4)); }

DEVI bf16x8 cvt8(const float* p) {
  float4 a = *reinterpret_cast<const float4*>(p);
  float4 b = *reinterpret_cast<const float4*>(p + 4);
  bf16x8 r;
  r[0] = (short)f2bf(a.x); r[1] = (short)f2bf(a.y); r[2] = (short)f2bf(a.z); r[3] = (short)f2bf(a.w);
  r[4] = (short)f2bf(b.x); r[5] = (short)f2bf(b.y); r[6] = (short)f2bf(b.z); r[7] = (short)f2bf(b.w);
  return r;
}

// ---------------- prologue: fp32 -> bf16 casts ----------------
__global__ __launch_bounds__(256) void cvt_qk(const float* __restrict__ q, const float* __restrict__ k,
                                              unsigned short* __restrict__ qb, unsigned short* __restrict__ kb)
{
  const long i = ((long)blockIdx.x * 256 + threadIdx.x) * 4;
  if (i >= QKV_ELEMS) return;
  const float4 a = *reinterpret_cast<const float4*>(q + i);
  ushort4 oa; oa.x = f2bf(a.x); oa.y = f2bf(a.y); oa.z = f2bf(a.z); oa.w = f2bf(a.w);
  *reinterpret_cast<ushort4*>(qb + i) = oa;
  const float4 b = *reinterpret_cast<const float4*>(k + i);
  ushort4 ob; ob.x = f2bf(b.x); ob.y = f2bf(b.y); ob.z = f2bf(b.z); ob.w = f2bf(b.w);
  *reinterpret_cast<ushort4*>(kb + i) = ob;
}

// V [bh][s][d] fp32 -> Vt [bh][d][s] bf16
__global__ __launch_bounds__(256) void cvt_vt(const float* __restrict__ v, unsigned short* __restrict__ vt)
{
  __shared__ float tile[64][65];
  const int bh = blockIdx.x >> 5;
  const int s0 = (blockIdx.x & 31) << 6;
  const int t  = threadIdx.x;
  {
    const int c = (t & 15) << 2;
    const float* src = v + ((long)bh * Ss + s0) * Dd;
    for (int rr = (t >> 4); rr < 64; rr += 16) {
      const float4 a = *reinterpret_cast<const float4*>(src + rr * Dd + c);
      tile[rr][c] = a.x; tile[rr][c + 1] = a.y; tile[rr][c + 2] = a.z; tile[rr][c + 3] = a.w;
    }
  }
  __syncthreads();
  {
    const int d  = t >> 2;
    const int sc = (t & 3) << 4;
    unsigned short* dst = vt + ((long)bh * Dd + d) * Ss + s0 + sc;
    u16x8 v0, v1;
#pragma unroll
    for (int j = 0; j < 8; ++j) v0[j] = f2bf(tile[sc + j][d]);
#pragma unroll
    for (int j = 0; j < 8; ++j) v1[j] = f2bf(tile[sc + 8 + j][d]);
    *reinterpret_cast<u16x8*>(dst)     = v0;
    *reinterpret_cast<u16x8*>(dst + 8) = v1;
  }
}

// ---------------- main fused attention ----------------
// 1 block = 16 q-rows of one (b,h); 4 waves; P (exp scores) kept in swizzled bf16 LDS.
template<bool PRE>
__global__ __launch_bounds__(256, 2)
void attn_main(const float* __restrict__ qf, const float* __restrict__ kf,
               const float* __restrict__ vf, const int* __restrict__ mask,
               const unsigned short* __restrict__ qb,
               const unsigned short* __restrict__ kbp,
               const unsigned short* __restrict__ vt,
               float* __restrict__ out, float* __restrict__ attn)
{
  __shared__ __align__(16) char Pb[16 * 2048 * 2];
  __shared__ float rpart[4][16];
  __shared__ float rinv[16];

  const int tid  = threadIdx.x;
  const int wave = tid >> 6;
  const int lane = tid & 63;
  const int l15  = lane & 15;
  const int lg   = lane >> 4;

  const int bh    = blockIdx.x >> 7;
  const int qbase = (blockIdx.x & 127) << 4;

  // Q fragments (B operand of swapped QK^T): n = q = lane&15, k-dim = d
  bf16x8 qfrag0, qfrag1;
  {
    const long qrow = (long)(bh * Ss + qbase + l15) * Dd + lg * 8;
    if (PRE) {
      qfrag0 = *reinterpret_cast<const bf16x8*>(qb + qrow);
      qfrag1 = *reinterpret_cast<const bf16x8*>(qb + qrow + 32);
    } else {
      qfrag0 = cvt8(qf + qrow);
      qfrag1 = cvt8(qf + qrow + 32);
    }
  }

  float psum = 0.f;
  const long mrow = (long)(bh * Ss + qbase + l15) * Ss;   // this lane's q-row in mask

  // Phase 1: S^T = K·Q^T per 16-key tile; exp+mask; scatter into LDS; rowsum
  for (int kt = 0; kt < Ss; kt += 64) {
    const int key0 = kt + (wave << 4);
    bf16x8 kfrag0, kfrag1;
    const long krow = (long)(bh * Ss + key0 + l15) * Dd + lg * 8;
    if (PRE) {
      kfrag0 = *reinterpret_cast<const bf16x8*>(kbp + krow);
      kfrag1 = *reinterpret_cast<const bf16x8*>(kbp + krow + 32);
    } else {
      kfrag0 = cvt8(kf + krow);
      kfrag1 = cvt8(kf + krow + 32);
    }
    const int k0 = key0 + (lg << 2);                      // 4 consecutive keys per lane
    const int4 m4 = *reinterpret_cast<const int4*>(mask + mrow + k0);
    f32x4 acc = {0.f, 0.f, 0.f, 0.f};
    acc = __builtin_amdgcn_mfma_f32_16x16x32_bf16(kfrag0, qfrag0, acc, 0, 0, 0);
    acc = __builtin_amdgcn_mfma_f32_16x16x32_bf16(kfrag1, qfrag1, acc, 0, 0, 0);
    const float p0 = m4.x ? __expf(acc[0] * SCALE) : 0.f;
    const float p1 = m4.y ? __expf(acc[1] * SCALE) : 0.f;
    const float p2 = m4.z ? __expf(acc[2] * SCALE) : 0.f;
    const float p3 = m4.w ? __expf(acc[3] * SCALE) : 0.f;
    psum += (p0 + p1) + (p2 + p3);
    uint2 w2;
    w2.x = (unsigned)f2bf(p0) | ((unsigned)f2bf(p1) << 16);
    w2.y = (unsigned)f2bf(p2) | ((unsigned)f2bf(p3) << 16);
    *reinterpret_cast<uint2*>(Pb + pidx(l15, k0)) = w2;
  }

  // row-sum reduce: lanes with equal l15 share a q-row
  psum += __shfl_xor(psum, 16);
  psum += __shfl_xor(psum, 32);
  if (lane < 16) rpart[wave][l15] = psum;
  __syncthreads();
  if (tid < 16) {
    const float t = rpart[0][tid] + rpart[1][tid] + rpart[2][tid] + rpart[3][tid];
    rinv[tid] = (t > 0.f) ? (1.f / t) : 0.f;
  }
  __syncthreads();

  // Phase 2: normalize + write attn (fp32, coalesced float4)
  {
    const int r  = tid >> 4;
    const int cs = (tid & 15) << 3;
    const float inv = rinv[r];
    float* arow = attn + (long)(bh * Ss + qbase + r) * Ss;
#pragma unroll
    for (int it = 0; it < 16; ++it) {
      const int c0 = cs + (it << 7);
      const uint4 pk = *reinterpret_cast<const uint4*>(Pb + pidx(r, c0));
      float4 o0, o1;
      o0.x = bflo(pk.x) * inv; o0.y = bfhi(pk.x) * inv;
      o0.z = bflo(pk.y) * inv; o0.w = bfhi(pk.y) * inv;
      o1.x = bflo(pk.z) * inv; o1.y = bfhi(pk.z) * inv;
      o1.z = bflo(pk.w) * inv; o1.w = bfhi(pk.w) * inv;
      *reinterpret_cast<float4*>(arow + c0)     = o0;
      *reinterpret_cast<float4*>(arow + c0 + 4) = o1;
    }
  }

  // Phase 3: O = P·V via MFMA; wave w owns d-columns [16w, 16w+16)
  {
    const int dcol = (wave << 4) + l15;
    f32x4 oacc = {0.f, 0.f, 0.f, 0.f};
    const unsigned short* vrow = PRE ? (vt + (long)(bh * Dd + dcol) * Ss) : nullptr;
    const float* vcolf = PRE ? nullptr : (vf + (long)bh * Ss * Dd + dcol);
    for (int kk = 0; kk < Ss; kk += 32) {
      const int ka = kk + (lg << 3);
      const bf16x8 afrag = *reinterpret_cast<const bf16x8*>(Pb + pidx(l15, ka));
      bf16x8 bfrag;
      if (PRE) {
        bfrag = *reinterpret_cast<const bf16x8*>(vrow + ka);
      } else {
#pragma unroll
        for (int e = 0; e < 8; ++e) bfrag[e] = (short)f2bf(vcolf[(long)(ka + e) * Dd]);
      }
      oacc = __builtin_amdgcn_mfma_f32_16x16x32_bf16(afrag, bfrag, oacc, 0, 0, 0);
    }
    float* obase = out + (long)(bh * Ss + qbase) * Dd + dcol;
#pragma unroll
    for (int rg = 0; rg < 4; ++rg) {
      const int qrow = (lg << 2) + rg;
      obase[qrow * Dd] = oacc[rg] * rinv[qrow];
    }
  }
}

extern "C" void kernel_launch(void* const* d_in, const int* in_sizes, int n_in,
                              void* d_out, int out_size, void* d_ws, size_t ws_size,
                              hipStream_t stream)
{
  const float* q    = (const float*)d_in[0];
  const float* k    = (const float*)d_in[1];
  const float* v    = (const float*)d_in[2];
  const int*   mask = (const int*)d_in[3];
  float* out  = (float*)d_out;
  float* attn = out + QKV_ELEMS;

  const size_t need = (size_t)QKV_ELEMS * 2 * 3;   // qb + kb + vt, bf16
  if (ws_size >= need) {
    unsigned short* qb = (unsigned short*)d_ws;
    unsigned short* kb = qb + QKV_ELEMS;
    unsigned short* vt = kb + QKV_ELEMS;
    hipLaunchKernelGGL(cvt_qk, dim3((unsigned)(QKV_ELEMS / 1024)), dim3(256), 0, stream, q, k, qb, kb);
    hipLaunchKernelGGL(cvt_vt, dim3(BH * 32), dim3(256), 0, stream, v, vt);
    hipLaunchKernelGGL((attn_main<true>), dim3(BH * 128), dim3(256), 0, stream,
                       q, k, v, mask, qb, kb, vt, out, attn);
  } else {
    hipLaunchKernelGGL((attn_main<false>), dim3(BH * 128), dim3(256), 0, stream,
                       q, k, v, mask, nullptr, nullptr, nullptr, out, attn);
  }
}